// Round 1
// baseline (1889.767 us; speedup 1.0000x reference)
//
#include <hip/hip_runtime.h>
#include <stdint.h>

// ---------- problem constants ----------
#define BATCH 1024
#define NVIEW 8
#define JN_   21
#define VTOK  168              // NVIEW*JN_
#define FDIM  512
#define NHEAD 4
#define DHEAD 128
#define MROWS (BATCH*VTOK)     // 172032
#define NEGF  (-4294967296.0f) // float32(-2^32+1)
#define SCALE_QK 0.08838834764831845f  // 1/sqrt(128)

typedef __attribute__((ext_vector_type(8))) short s8v;
typedef __attribute__((ext_vector_type(4))) short s4v;
typedef __attribute__((ext_vector_type(4))) float f4v;

static __device__ __forceinline__ short f2bf(float f){
  unsigned u = __builtin_bit_cast(unsigned, f);
  unsigned r = (u + 0x7FFFu + ((u >> 16) & 1u)) >> 16;  // RNE
  return (short)(unsigned short)r;
}
static __device__ __forceinline__ float bf2f(short s){
  unsigned u = ((unsigned)(unsigned short)s) << 16;
  return __builtin_bit_cast(float, u);
}
static __device__ __forceinline__ s8v ld_b64x2(const short* p){
  s8v r;
  *(s4v*)&r       = *(const s4v*)p;
  *((s4v*)&r + 1) = *(const s4v*)(p + 4);
  return r;
}

#define GL16(gp, lp) __builtin_amdgcn_global_load_lds( \
    (__attribute__((address_space(1))) void*)(gp), \
    (__attribute__((address_space(3))) void*)(lp), 16, 0, 0)

// ---------- K0: fp32 -> bf16 weight conversion (wq|wk|wv|fcw|fc1|fc2) ----------
__global__ __launch_bounds__(256) void convert_w(
    const float* __restrict__ wq, const float* __restrict__ wk,
    const float* __restrict__ wv, const float* __restrict__ fcw,
    const float* __restrict__ fc1, const float* __restrict__ fc2,
    short* __restrict__ dst){
  int id = blockIdx.x * 256 + threadIdx.x;   // 393216 total
  int e = id * 4;
  int seg = e >> 18;            // 262144 elems per matrix
  int off = e & 262143;
  const float* s = seg==0?wq: seg==1?wk: seg==2?wv: seg==3?fcw: seg==4?fc1: fc2;
  float4 u = *(const float4*)(s + off);
  s4v o; o[0]=f2bf(u.x); o[1]=f2bf(u.y); o[2]=f2bf(u.z); o[3]=f2bf(u.w);
  *(s4v*)(dst + e) = o;
}

// ---------- K1: LN1 row kernel: h = LN(x) in bf16.  1 wave per row ----------
__global__ __launch_bounds__(256) void ln1_kernel(
    const float* __restrict__ x, const float* __restrict__ g,
    const float* __restrict__ bb, short* __restrict__ h){
  int row  = blockIdx.x * 4 + (threadIdx.x >> 6);
  int lane = threadIdx.x & 63;
  size_t base = (size_t)row * 512 + lane * 8;
  float4 u0 = *(const float4*)(x + base);
  float4 u1 = *(const float4*)(x + base + 4);
  float s = u0.x+u0.y+u0.z+u0.w + u1.x+u1.y+u1.z+u1.w;
  float q = u0.x*u0.x+u0.y*u0.y+u0.z*u0.z+u0.w*u0.w
          + u1.x*u1.x+u1.y*u1.y+u1.z*u1.z+u1.w*u1.w;
  #pragma unroll
  for (int o = 1; o < 64; o <<= 1){ s += __shfl_xor(s,o); q += __shfl_xor(q,o); }
  float mu = s * (1.f/512.f);
  float rstd = rsqrtf(q*(1.f/512.f) - mu*mu + 1e-6f);
  float4 g0 = *(const float4*)(g + lane*8),  g1 = *(const float4*)(g + lane*8 + 4);
  float4 b0 = *(const float4*)(bb + lane*8), b1 = *(const float4*)(bb + lane*8 + 4);
  s8v o_;
  o_[0]=f2bf((u0.x-mu)*rstd*g0.x+b0.x); o_[1]=f2bf((u0.y-mu)*rstd*g0.y+b0.y);
  o_[2]=f2bf((u0.z-mu)*rstd*g0.z+b0.z); o_[3]=f2bf((u0.w-mu)*rstd*g0.w+b0.w);
  o_[4]=f2bf((u1.x-mu)*rstd*g1.x+b1.x); o_[5]=f2bf((u1.y-mu)*rstd*g1.y+b1.y);
  o_[6]=f2bf((u1.z-mu)*rstd*g1.z+b1.z); o_[7]=f2bf((u1.w-mu)*rstd*g1.w+b1.w);
  *(s8v*)(h + base) = o_;
}

// ---------- K4b: x2 = x + y ; g2 = LN2(x2).  1 wave per row ----------
__global__ __launch_bounds__(256) void resid_ln(
    const float* __restrict__ x, const short* __restrict__ y,
    const float* __restrict__ g, const float* __restrict__ bb,
    float* __restrict__ x2, short* __restrict__ g2){
  int row  = blockIdx.x * 4 + (threadIdx.x >> 6);
  int lane = threadIdx.x & 63;
  size_t base = (size_t)row * 512 + lane * 8;
  float4 u0 = *(const float4*)(x + base);
  float4 u1 = *(const float4*)(x + base + 4);
  s8v yv = *(const s8v*)(y + base);
  float v[8];
  v[0]=u0.x+bf2f(yv[0]); v[1]=u0.y+bf2f(yv[1]); v[2]=u0.z+bf2f(yv[2]); v[3]=u0.w+bf2f(yv[3]);
  v[4]=u1.x+bf2f(yv[4]); v[5]=u1.y+bf2f(yv[5]); v[6]=u1.z+bf2f(yv[6]); v[7]=u1.w+bf2f(yv[7]);
  *(float4*)(x2 + base)     = make_float4(v[0],v[1],v[2],v[3]);
  *(float4*)(x2 + base + 4) = make_float4(v[4],v[5],v[6],v[7]);
  float s = 0.f, q = 0.f;
  #pragma unroll
  for (int i = 0; i < 8; i++){ s += v[i]; q += v[i]*v[i]; }
  #pragma unroll
  for (int o = 1; o < 64; o <<= 1){ s += __shfl_xor(s,o); q += __shfl_xor(q,o); }
  float mu = s * (1.f/512.f);
  float rstd = rsqrtf(q*(1.f/512.f) - mu*mu + 1e-6f);
  float4 g0 = *(const float4*)(g + lane*8),  g1 = *(const float4*)(g + lane*8 + 4);
  float4 b0 = *(const float4*)(bb + lane*8), b1 = *(const float4*)(bb + lane*8 + 4);
  s8v o_;
  o_[0]=f2bf((v[0]-mu)*rstd*g0.x+b0.x); o_[1]=f2bf((v[1]-mu)*rstd*g0.y+b0.y);
  o_[2]=f2bf((v[2]-mu)*rstd*g0.z+b0.z); o_[3]=f2bf((v[3]-mu)*rstd*g0.w+b0.w);
  o_[4]=f2bf((v[4]-mu)*rstd*g1.x+b1.x); o_[5]=f2bf((v[5]-mu)*rstd*g1.y+b1.y);
  o_[6]=f2bf((v[6]-mu)*rstd*g1.z+b1.z); o_[7]=f2bf((v[7]-mu)*rstd*g1.w+b1.w);
  *(s8v*)(g2 + base) = o_;
}

// ---------- GEMM template: C[i][j] = sum_k A[i][k]*B[j][k]  (both bf16, K=512) ----------
// MODE 0: A=h,        B=[wq|wk] (N=1024) -> q_ws/k_ws [B,NH,V,128] (+bq/bk)
// MODE 1: A=wv(M=512),B=h (N=172032)     -> vt_ws [B,NH,128,V]     (+bv)
// MODE 2: A=attn_out, B=fc_w             -> y bf16 [M,512]          (+fc_b)
// MODE 3: A=g2,       B=fc1_w            -> a1 = relu(.) bf16       (+fc1_b)
// MODE 4: A=a1,       B=fc2_w            -> d_out f32 = . + fc2_b + x2
template<int MODE>
__global__ __launch_bounds__(256) void gemm_bt(
    const short* __restrict__ A, const short* __restrict__ Bm,
    const float* __restrict__ bias0, const float* __restrict__ bias1,
    const float* __restrict__ aux, short* __restrict__ out0,
    short* __restrict__ out1, float* __restrict__ outf){
  __shared__ short As[128*64];
  __shared__ short Bs[128*64];
  int tid = threadIdx.x, lane = tid & 63;
  int wid = tid >> 6, wr = wid >> 1, wc = wid & 1;
  int lg = lane >> 4, l15 = lane & 15;
  size_t mt, nt;
  if (MODE == 1){ mt = blockIdx.x; nt = blockIdx.y; }
  else          { nt = blockIdx.x; mt = blockIdx.y; }
  size_t m0 = mt * 128, n0 = nt * 128;
  const short* Ab = A + m0 * 512;
  const short* Bb = Bm + n0 * 512;
  f4v zf = {0.f,0.f,0.f,0.f};
  f4v acc[4][4];
  #pragma unroll
  for (int m=0;m<4;m++)
    #pragma unroll
    for (int n=0;n<4;n++) acc[m][n] = zf;

  for (int kt = 0; kt < 512; kt += 64){
    #pragma unroll
    for (int i = 0; i < 4; i++){
      int c = tid + i * 256;          // 1024 16B-chunks per tile
      int row = c >> 3, col = (c & 7) * 8;
      GL16(Ab + (size_t)row*512 + kt + col, &As[c*8]);
      GL16(Bb + (size_t)row*512 + kt + col, &Bs[c*8]);
    }
    __syncthreads();
    #pragma unroll
    for (int kk = 0; kk < 64; kk += 32){
      s8v af[4], bfr[4];
      #pragma unroll
      for (int m=0;m<4;m++) af[m]  = *(const s8v*)&As[(wr*64 + m*16 + l15)*64 + kk + lg*8];
      #pragma unroll
      for (int n=0;n<4;n++) bfr[n] = *(const s8v*)&Bs[(wc*64 + n*16 + l15)*64 + kk + lg*8];
      #pragma unroll
      for (int m=0;m<4;m++)
        #pragma unroll
        for (int n=0;n<4;n++)
          acc[m][n] = __builtin_amdgcn_mfma_f32_16x16x32_bf16(af[m], bfr[n], acc[m][n], 0,0,0);
    }
    __syncthreads();
  }

  #pragma unroll
  for (int m=0;m<4;m++)
  #pragma unroll
  for (int n=0;n<4;n++)
  #pragma unroll
  for (int r=0;r<4;r++){
    int rowL = wr*64 + m*16 + lg*4 + r;
    int colL = wc*64 + n*16 + l15;
    size_t gm = m0 + rowL, gn = n0 + colL;
    float val = acc[m][n][r];
    if (MODE == 0){
      int nn = (int)gn;
      val += (nn < 512) ? bias0[nn] : bias1[nn - 512];
      int head = (nn >> 7) & 3, d = nn & 127;
      size_t b = gm / 168, tok = gm - b * 168;
      size_t idx = ((b*4 + head)*168 + tok)*128 + d;
      ((nn < 512) ? out0 : out1)[idx] = f2bf(val);
    } else if (MODE == 1){
      val += bias0[gm];
      int hh = ((int)gm >> 7) & 3, d = (int)gm & 127;
      size_t b = gn / 168, tok = gn - b * 168;
      out0[((b*4 + hh)*128 + d)*168 + tok] = f2bf(val);
    } else if (MODE == 2 || MODE == 3){
      val += bias0[gn];
      if (MODE == 3) val = fmaxf(val, 0.f);
      out0[gm*512 + gn] = f2bf(val);
    } else {
      val += bias0[gn] + aux[gm*512 + gn];
      outf[gm*512 + gn] = val;
    }
  }
}

// ---------- K3: attention, one block per (b, head), 4 waves ----------
// LDS: Qs[176][132] | Ks[176][132] | Ps[176][200] | wvm[16];  Vts[128][200] overlays Qs/Ks
__global__ __launch_bounds__(256) void attn_kernel(
    const short* __restrict__ qg_, const short* __restrict__ kg_,
    const short* __restrict__ vtg_, const int* __restrict__ valid,
    short* __restrict__ outp){
  __shared__ int4 smemv[10212];          // 163392 B
  char* smem = (char*)smemv;
  short* Qs  = (short*)smem;             // [176][132]
  short* Ks  = (short*)(smem + 46464);   // [176][132]
  short* Ps  = (short*)(smem + 92928);   // [176][200]
  float* wvm = (float*)(smem + 163328);  // [16]
  short* Vts = (short*)smem;             // [128][200] overlay

  int tid = threadIdx.x, lane = tid & 63, wid = tid >> 6;
  int lg = lane >> 4, l15 = lane & 15;
  int bh = blockIdx.x, b = bh >> 2, hh = bh & 3;
  const short* qg  = qg_  + (size_t)bh * (168*128);
  const short* kg  = kg_  + (size_t)bh * (168*128);
  const short* vtg = vtg_ + (size_t)bh * (128*168);

  if (tid < 16) wvm[tid] = (tid < 8) ? ((valid[b*8 + tid] == 0) ? NEGF : 0.0f) : 0.0f;

  // stage Q,K (stride 132 to avoid ds_read bank conflicts)
  for (int c = tid; c < 2688; c += 256){
    int row = c >> 4, cc = c & 15;
    int4 u = *(const int4*)(qg + (size_t)c * 8);
    int4 w = *(const int4*)(kg + (size_t)c * 8);
    int2* dq = (int2*)&Qs[row*132 + cc*8];
    dq[0] = make_int2(u.x,u.y); dq[1] = make_int2(u.z,u.w);
    int2* dk = (int2*)&Ks[row*132 + cc*8];
    dk[0] = make_int2(w.x,w.y); dk[1] = make_int2(w.z,w.w);
  }
  { // zero pad rows 168..175 of Qs,Ks
    int bu = tid >> 7, rr = 168 + ((tid >> 4) & 7), cc = tid & 15;
    short* base = bu ? Ks : Qs;
    int2* dz = (int2*)&base[rr*132 + cc*8];
    dz[0] = make_int2(0,0); dz[1] = make_int2(0,0);
  }
  __syncthreads();

  int row0 = wid * 48;
  int nrf  = (wid == 3) ? 2 : 3;   // row fragments of 16 per wave
  f4v zf = {0.f,0.f,0.f,0.f};
  f4v accS[3][11];
  #pragma unroll
  for (int m=0;m<3;m++)
    #pragma unroll
    for (int n=0;n<11;n++) accS[m][n] = zf;

  // S = Q @ K^T
  #pragma unroll
  for (int kf = 0; kf < 4; kf++){
    s8v aq[3];
    #pragma unroll
    for (int m=0;m<3;m++) if (m < nrf)
      aq[m] = ld_b64x2(&Qs[(row0 + m*16 + l15)*132 + kf*32 + lg*8]);
    #pragma unroll
    for (int n=0;n<11;n++){
      s8v bk = ld_b64x2(&Ks[(n*16 + l15)*132 + kf*32 + lg*8]);
      #pragma unroll
      for (int m=0;m<3;m++) if (m < nrf)
        accS[m][n] = __builtin_amdgcn_mfma_f32_16x16x32_bf16(aq[m], bk, accS[m][n], 0,0,0);
    }
  }

  // mask + softmax (row reduce across 16-lane groups), write unnormalized P
  float inv_[3][4];
  #pragma unroll
  for (int m=0;m<3;m++){
    if (m >= nrf) continue;
    #pragma unroll
    for (int r=0;r<4;r++){
      int qtok = row0 + m*16 + lg*4 + r;
      float mq = wvm[qtok / 21];            // qtok<=175 -> idx<=8, wvm[8..15]=0
      float mx = -INFINITY;
      #pragma unroll
      for (int n=0;n<11;n++){
        int ktok = n*16 + l15;
        float t = (ktok < 168) ? (accS[m][n][r]*SCALE_QK + mq + wvm[ktok/21]) : -INFINITY;
        accS[m][n][r] = t;
        mx = fmaxf(mx, t);
      }
      mx = fmaxf(mx, __shfl_xor(mx,1)); mx = fmaxf(mx, __shfl_xor(mx,2));
      mx = fmaxf(mx, __shfl_xor(mx,4)); mx = fmaxf(mx, __shfl_xor(mx,8));
      float sum = 0.f;
      #pragma unroll
      for (int n=0;n<11;n++){
        float p = __expf(accS[m][n][r] - mx);
        sum += p;
        Ps[qtok*200 + n*16 + l15] = f2bf(p);
      }
      sum += __shfl_xor(sum,1); sum += __shfl_xor(sum,2);
      sum += __shfl_xor(sum,4); sum += __shfl_xor(sum,8);
      inv_[m][r] = 1.0f / sum;
    }
  }
  // zero P pad cols 176..191 for this wave's rows
  for (int i = lane; i < nrf*16*4; i += 64){
    int rr = row0 + (i >> 2), qq = i & 3;
    *(int2*)&Ps[rr*200 + 176 + qq*4] = make_int2(0,0);
  }
  __syncthreads();

  // stage V^T (overlays Q/K region), pad cols 168..199 to zero
  for (int c = tid; c < 2688; c += 256){
    int d = c / 21, vc = c - d*21;
    int4 u = *(const int4*)(vtg + (size_t)c * 8);
    *(int4*)&Vts[d*200 + vc*8] = u;
  }
  for (int c = tid; c < 512; c += 256){
    int d = c >> 2, qq = c & 3;
    *(int4*)&Vts[d*200 + 168 + qq*8] = make_int4(0,0,0,0);
  }
  __syncthreads();

  // O = P @ V
  f4v accO[3][8];
  #pragma unroll
  for (int m=0;m<3;m++)
    #pragma unroll
    for (int n=0;n<8;n++) accO[m][n] = zf;
  #pragma unroll
  for (int kf = 0; kf < 6; kf++){
    s8v ap[3];
    #pragma unroll
    for (int m=0;m<3;m++) if (m < nrf)
      ap[m] = *(const s8v*)&Ps[(row0 + m*16 + l15)*200 + kf*32 + lg*8];
    #pragma unroll
    for (int n=0;n<8;n++){
      s8v bv = *(const s8v*)&Vts[(n*16 + l15)*200 + kf*32 + lg*8];
      #pragma unroll
      for (int m=0;m<3;m++) if (m < nrf)
        accO[m][n] = __builtin_amdgcn_mfma_f32_16x16x32_bf16(ap[m], bv, accO[m][n], 0,0,0);
    }
  }

  // write attn_out [b*168+q][hh*128+d] bf16 (normalize by 1/rowsum)
  #pragma unroll
  for (int m=0;m<3;m++){
    if (m >= nrf) continue;
    #pragma unroll
    for (int r=0;r<4;r++){
      int qtok = row0 + m*16 + lg*4 + r;
      if (qtok < 168){
        float iv = inv_[m][r];
        size_t base = ((size_t)b*168 + qtok)*512 + hh*128;
        #pragma unroll
        for (int n=0;n<8;n++)
          outp[base + n*16 + l15] = f2bf(accO[m][n][r] * iv);
      }
    }
  }
}

// ---------- launch ----------
extern "C" void kernel_launch(void* const* d_in, const int* in_sizes, int n_in,
                              void* d_out, int out_size, void* d_ws, size_t ws_size,
                              hipStream_t stream) {
  const float* x     = (const float*)d_in[0];
  const int*   valid = (const int*)  d_in[1];
  const float* wq    = (const float*)d_in[2];
  const float* bq    = (const float*)d_in[3];
  const float* wk    = (const float*)d_in[4];
  const float* bk    = (const float*)d_in[5];
  const float* wv    = (const float*)d_in[6];
  const float* bv    = (const float*)d_in[7];
  const float* fcw   = (const float*)d_in[8];
  const float* fcb   = (const float*)d_in[9];
  const float* ln1g  = (const float*)d_in[10];
  const float* ln1b  = (const float*)d_in[11];
  const float* ln2g  = (const float*)d_in[12];
  const float* ln2b  = (const float*)d_in[13];
  const float* fc1w  = (const float*)d_in[14];
  const float* fc1b  = (const float*)d_in[15];
  const float* fc2w  = (const float*)d_in[16];
  const float* fc2b  = (const float*)d_in[17];

  char* ws = (char*)d_ws;
  // region layout (bytes); each bf16 [172032][512] slab = 176,160,768 B
  short* h       = (short*)(ws + 0LL);            // later: attn_out, then g2
  short* q_ws    = (short*)(ws + 176160768LL);    // later: y, then a1
  short* k_ws    = (short*)(ws + 352321536LL);    // later: x2 (fp32, spans k+vt)
  short* vt_ws   = (short*)(ws + 528482304LL);
  short* wb      = (short*)(ws + 704643072LL);    // bf16 weights [wq|wk|wv|fcw|fc1|fc2]
  short* attn_o  = h;
  short* y       = q_ws;
  float* x2      = (float*)(ws + 352321536LL);
  short* g2      = h;
  short* a1      = q_ws;
  float* outp    = (float*)d_out;

  convert_w<<<1536, 256, 0, stream>>>(wq, wk, wv, fcw, fc1w, fc2w, wb);
  ln1_kernel<<<MROWS/4, 256, 0, stream>>>(x, ln1g, ln1b, h);
  // QK projection (N=1024)
  gemm_bt<0><<<dim3(8, MROWS/128), 256, 0, stream>>>(h, wb, bq, bk, nullptr, q_ws, k_ws, nullptr);
  // V^T projection: wv @ h^T (M=512, N=172032)
  gemm_bt<1><<<dim3(4, MROWS/128), 256, 0, stream>>>(wb + 524288, h, bv, nullptr, nullptr, vt_ws, nullptr, nullptr);
  attn_kernel<<<BATCH*NHEAD, 256, 0, stream>>>(q_ws, k_ws, vt_ws, valid, attn_o);
  // output projection
  gemm_bt<2><<<dim3(4, MROWS/128), 256, 0, stream>>>(attn_o, wb + 786432, fcb, nullptr, nullptr, y, nullptr, nullptr);
  resid_ln<<<MROWS/4, 256, 0, stream>>>(x, y, ln2g, ln2b, x2, g2);
  // MLP
  gemm_bt<3><<<dim3(4, MROWS/128), 256, 0, stream>>>(g2, wb + 1048576, fc1b, nullptr, nullptr, a1, nullptr, nullptr);
  gemm_bt<4><<<dim3(4, MROWS/128), 256, 0, stream>>>(a1, wb + 1310720, fc2b, nullptr, x2, nullptr, nullptr, outp);
}

// Round 2
// 1854.018 us; speedup vs baseline: 1.0193x; 1.0193x over previous
//
#include <hip/hip_runtime.h>
#include <stdint.h>

// ---------- problem constants ----------
#define BATCH 1024
#define NVIEW 8
#define JN_   21
#define VTOK  168              // NVIEW*JN_
#define FDIM  512
#define NHEAD 4
#define DHEAD 128
#define MROWS (BATCH*VTOK)     // 172032
#define SCALE2 0.127517434f    // (1/sqrt(128)) * log2(e)

typedef __attribute__((ext_vector_type(8))) short s8v;
typedef __attribute__((ext_vector_type(4))) short s4v;
typedef __attribute__((ext_vector_type(4))) float f4v;

static __device__ __forceinline__ short f2bf(float f){
  unsigned u = __builtin_bit_cast(unsigned, f);
  unsigned r = (u + 0x7FFFu + ((u >> 16) & 1u)) >> 16;  // RNE
  return (short)(unsigned short)r;
}
static __device__ __forceinline__ float bf2f(short s){
  unsigned u = ((unsigned)(unsigned short)s) << 16;
  return __builtin_bit_cast(float, u);
}

#define GL16(gp, lp) __builtin_amdgcn_global_load_lds( \
    (__attribute__((address_space(1))) void*)(gp), \
    (__attribute__((address_space(3))) void*)(lp), 16, 0, 0)

// ---------- K0: fp32 -> bf16 weight conversion (wq|wk|wv|fcw|fc1|fc2) ----------
__global__ __launch_bounds__(256) void convert_w(
    const float* __restrict__ wq, const float* __restrict__ wk,
    const float* __restrict__ wv, const float* __restrict__ fcw,
    const float* __restrict__ fc1, const float* __restrict__ fc2,
    short* __restrict__ dst){
  int id = blockIdx.x * 256 + threadIdx.x;   // 393216 total
  int e = id * 4;
  int seg = e >> 18;            // 262144 elems per matrix
  int off = e & 262143;
  const float* s = seg==0?wq: seg==1?wk: seg==2?wv: seg==3?fcw: seg==4?fc1: fc2;
  float4 u = *(const float4*)(s + off);
  s4v o; o[0]=f2bf(u.x); o[1]=f2bf(u.y); o[2]=f2bf(u.z); o[3]=f2bf(u.w);
  *(s4v*)(dst + e) = o;
}

// ---------- K1: LN1 row kernel: h = LN(x) in bf16.  1 wave per row ----------
__global__ __launch_bounds__(256) void ln1_kernel(
    const float* __restrict__ x, const float* __restrict__ g,
    const float* __restrict__ bb, short* __restrict__ h){
  int row  = blockIdx.x * 4 + (threadIdx.x >> 6);
  int lane = threadIdx.x & 63;
  size_t base = (size_t)row * 512 + lane * 8;
  float4 u0 = *(const float4*)(x + base);
  float4 u1 = *(const float4*)(x + base + 4);
  float s = u0.x+u0.y+u0.z+u0.w + u1.x+u1.y+u1.z+u1.w;
  float q = u0.x*u0.x+u0.y*u0.y+u0.z*u0.z+u0.w*u0.w
          + u1.x*u1.x+u1.y*u1.y+u1.z*u1.z+u1.w*u1.w;
  #pragma unroll
  for (int o = 1; o < 64; o <<= 1){ s += __shfl_xor(s,o); q += __shfl_xor(q,o); }
  float mu = s * (1.f/512.f);
  float rstd = rsqrtf(q*(1.f/512.f) - mu*mu + 1e-6f);
  float4 g0 = *(const float4*)(g + lane*8),  g1 = *(const float4*)(g + lane*8 + 4);
  float4 b0 = *(const float4*)(bb + lane*8), b1 = *(const float4*)(bb + lane*8 + 4);
  s8v o_;
  o_[0]=f2bf((u0.x-mu)*rstd*g0.x+b0.x); o_[1]=f2bf((u0.y-mu)*rstd*g0.y+b0.y);
  o_[2]=f2bf((u0.z-mu)*rstd*g0.z+b0.z); o_[3]=f2bf((u0.w-mu)*rstd*g0.w+b0.w);
  o_[4]=f2bf((u1.x-mu)*rstd*g1.x+b1.x); o_[5]=f2bf((u1.y-mu)*rstd*g1.y+b1.y);
  o_[6]=f2bf((u1.z-mu)*rstd*g1.z+b1.z); o_[7]=f2bf((u1.w-mu)*rstd*g1.w+b1.w);
  *(s8v*)(h + base) = o_;
}

// ---------- K4b: x2 = x + y ; g2 = LN2(x2).  1 wave per row ----------
__global__ __launch_bounds__(256) void resid_ln(
    const float* __restrict__ x, const short* __restrict__ y,
    const float* __restrict__ g, const float* __restrict__ bb,
    float* __restrict__ x2, short* __restrict__ g2){
  int row  = blockIdx.x * 4 + (threadIdx.x >> 6);
  int lane = threadIdx.x & 63;
  size_t base = (size_t)row * 512 + lane * 8;
  float4 u0 = *(const float4*)(x + base);
  float4 u1 = *(const float4*)(x + base + 4);
  s8v yv = *(const s8v*)(y + base);
  float v[8];
  v[0]=u0.x+bf2f(yv[0]); v[1]=u0.y+bf2f(yv[1]); v[2]=u0.z+bf2f(yv[2]); v[3]=u0.w+bf2f(yv[3]);
  v[4]=u1.x+bf2f(yv[4]); v[5]=u1.y+bf2f(yv[5]); v[6]=u1.z+bf2f(yv[6]); v[7]=u1.w+bf2f(yv[7]);
  *(float4*)(x2 + base)     = make_float4(v[0],v[1],v[2],v[3]);
  *(float4*)(x2 + base + 4) = make_float4(v[4],v[5],v[6],v[7]);
  float s = 0.f, q = 0.f;
  #pragma unroll
  for (int i = 0; i < 8; i++){ s += v[i]; q += v[i]*v[i]; }
  #pragma unroll
  for (int o = 1; o < 64; o <<= 1){ s += __shfl_xor(s,o); q += __shfl_xor(q,o); }
  float mu = s * (1.f/512.f);
  float rstd = rsqrtf(q*(1.f/512.f) - mu*mu + 1e-6f);
  float4 g0 = *(const float4*)(g + lane*8),  g1 = *(const float4*)(g + lane*8 + 4);
  float4 b0 = *(const float4*)(bb + lane*8), b1 = *(const float4*)(bb + lane*8 + 4);
  s8v o_;
  o_[0]=f2bf((v[0]-mu)*rstd*g0.x+b0.x); o_[1]=f2bf((v[1]-mu)*rstd*g0.y+b0.y);
  o_[2]=f2bf((v[2]-mu)*rstd*g0.z+b0.z); o_[3]=f2bf((v[3]-mu)*rstd*g0.w+b0.w);
  o_[4]=f2bf((v[4]-mu)*rstd*g1.x+b1.x); o_[5]=f2bf((v[5]-mu)*rstd*g1.y+b1.y);
  o_[6]=f2bf((v[6]-mu)*rstd*g1.z+b1.z); o_[7]=f2bf((v[7]-mu)*rstd*g1.w+b1.w);
  *(s8v*)(g2 + base) = o_;
}

// ---------- GEMM template: C[i][j] = sum_k A[i][k]*B[j][k]  (both bf16, K=512) ----------
template<int MODE>
__global__ __launch_bounds__(256) void gemm_bt(
    const short* __restrict__ A, const short* __restrict__ Bm,
    const float* __restrict__ bias0, const float* __restrict__ bias1,
    const float* __restrict__ aux, short* __restrict__ out0,
    short* __restrict__ out1, float* __restrict__ outf){
  __shared__ short As[128*64];
  __shared__ short Bs[128*64];
  int tid = threadIdx.x, lane = tid & 63;
  int wid = tid >> 6, wr = wid >> 1, wc = wid & 1;
  int lg = lane >> 4, l15 = lane & 15;
  // T1: XCD-aware bijective swizzle (nwg % 8 == 0 for all launches here)
  int nwg  = gridDim.x * gridDim.y;
  int flat = blockIdx.y * gridDim.x + blockIdx.x;
  int cpx  = nwg >> 3;
  int swz  = (flat & 7) * cpx + (flat >> 3);
  int bx = swz % gridDim.x, by = swz / gridDim.x;
  size_t mt, nt;
  if (MODE == 1){ mt = bx; nt = by; }
  else          { nt = bx; mt = by; }
  size_t m0 = mt * 128, n0 = nt * 128;
  const short* Ab = A + m0 * 512;
  const short* Bb = Bm + n0 * 512;
  f4v zf = {0.f,0.f,0.f,0.f};
  f4v acc[4][4];
  #pragma unroll
  for (int m=0;m<4;m++)
    #pragma unroll
    for (int n=0;n<4;n++) acc[m][n] = zf;

  for (int kt = 0; kt < 512; kt += 64){
    #pragma unroll
    for (int i = 0; i < 4; i++){
      int c = tid + i * 256;          // 1024 16B-chunks per tile
      int row = c >> 3, col = (c & 7) * 8;
      GL16(Ab + (size_t)row*512 + kt + col, &As[c*8]);
      GL16(Bb + (size_t)row*512 + kt + col, &Bs[c*8]);
    }
    __syncthreads();
    #pragma unroll
    for (int kk = 0; kk < 64; kk += 32){
      s8v af[4], bfr[4];
      #pragma unroll
      for (int m=0;m<4;m++) af[m]  = *(const s8v*)&As[(wr*64 + m*16 + l15)*64 + kk + lg*8];
      #pragma unroll
      for (int n=0;n<4;n++) bfr[n] = *(const s8v*)&Bs[(wc*64 + n*16 + l15)*64 + kk + lg*8];
      #pragma unroll
      for (int m=0;m<4;m++)
        #pragma unroll
        for (int n=0;n<4;n++)
          acc[m][n] = __builtin_amdgcn_mfma_f32_16x16x32_bf16(af[m], bfr[n], acc[m][n], 0,0,0);
    }
    __syncthreads();
  }

  #pragma unroll
  for (int m=0;m<4;m++)
  #pragma unroll
  for (int n=0;n<4;n++)
  #pragma unroll
  for (int r=0;r<4;r++){
    int rowL = wr*64 + m*16 + lg*4 + r;
    int colL = wc*64 + n*16 + l15;
    size_t gm = m0 + rowL, gn = n0 + colL;
    float val = acc[m][n][r];
    if (MODE == 0){
      int nn = (int)gn;
      val += (nn < 512) ? bias0[nn] : bias1[nn - 512];
      int head = (nn >> 7) & 3, d = nn & 127;
      size_t b = gm / 168, tok = gm - b * 168;
      size_t idx = ((b*4 + head)*168 + tok)*128 + d;
      ((nn < 512) ? out0 : out1)[idx] = f2bf(val);
    } else if (MODE == 1){
      val += bias0[gm];
      int hh = ((int)gm >> 7) & 3, d = (int)gm & 127;
      size_t b = gn / 168, tok = gn - b * 168;
      out0[((b*4 + hh)*128 + d)*168 + tok] = f2bf(val);
    } else if (MODE == 2 || MODE == 3){
      val += bias0[gn];
      if (MODE == 3) val = fmaxf(val, 0.f);
      out0[gm*512 + gn] = f2bf(val);
    } else {
      val += bias0[gn] + aux[gm*512 + gn];
      outf[gm*512 + gn] = val;
    }
  }
}

// ---------- K3 v2: attention, one block per (b, head), 4 independent waves ----------
// LDS: only P [176][200] bf16 = 70,400 B -> 2 blocks/CU. No barriers at all:
// Q/K/Vt MFMA fragments are read directly from global (L2-resident per block),
// P regions are per-wave disjoint.
__global__ __launch_bounds__(256, 2) void attn_kernel(
    const short* __restrict__ qg_, const short* __restrict__ kg_,
    const short* __restrict__ vtg_, const int* __restrict__ valid,
    short* __restrict__ outp){
  __shared__ short Ps[176*200];

  int tid = threadIdx.x, lane = tid & 63, wid = tid >> 6;
  int lg = lane >> 4, l15 = lane & 15;
  int bh = blockIdx.x, b = bh >> 2, hh = bh & 3;
  const short* qg  = qg_  + (size_t)bh * (168*128);
  const short* kg  = kg_  + (size_t)bh * (168*128);
  const short* vtg = vtg_ + (size_t)bh * (128*168);

  // mask bits: bit v == 1 -> view v valid. All-invalid => constant shift => treat all valid.
  int bits = 0;
  #pragma unroll
  for (int v = 0; v < 8; v++) bits |= (valid[b*8 + v] != 0) << v;
  if (bits == 0) bits = 255;
  // per-lane additive mask (in log2 domain) for the 11 k-fragments; ktok>=168 -> masked
  float wk2[11];
  #pragma unroll
  for (int n = 0; n < 11; n++){
    int kt = n*16 + l15;
    int view = (kt * 781) >> 14;            // kt/21, exact for kt<176
    wk2[n] = ((bits >> view) & 1) ? 0.0f : -1.0e9f;
  }

  int row0 = wid * 48;
  int nrf  = (wid == 3) ? 2 : 3;   // 16-row fragments per wave (rows 144..175 for wid3)
  f4v zf = {0.f,0.f,0.f,0.f};
  f4v accS[3][11];
  #pragma unroll
  for (int m=0;m<3;m++)
    #pragma unroll
    for (int n=0;n<11;n++) accS[m][n] = zf;

  // S = Q @ K^T — fragments straight from global
  #pragma unroll
  for (int kf = 0; kf < 4; kf++){
    s8v aq[3];
    #pragma unroll
    for (int m=0;m<3;m++) if (m < nrf)
      aq[m] = *(const s8v*)(qg + (size_t)(row0 + m*16 + l15)*128 + kf*32 + lg*8);
    #pragma unroll
    for (int n=0;n<11;n++){
      s8v bk = *(const s8v*)(kg + (size_t)(n*16 + l15)*128 + kf*32 + lg*8);
      #pragma unroll
      for (int m=0;m<3;m++) if (m < nrf)
        accS[m][n] = __builtin_amdgcn_mfma_f32_16x16x32_bf16(aq[m], bk, accS[m][n], 0,0,0);
    }
  }

  // softmax (no max-pass: values bounded, masked -> exp2(-1e9)=0), write unnormalized P
  float inv_[3][4];
  #pragma unroll
  for (int m=0;m<3;m++){
    if (m >= nrf) continue;
    #pragma unroll
    for (int r=0;r<4;r++){
      int qtok = row0 + m*16 + lg*4 + r;
      float sum = 0.f;
      #pragma unroll
      for (int n=0;n<11;n++){
        float p = exp2f(fmaf(accS[m][n][r], SCALE2, wk2[n]));
        sum += p;
        Ps[qtok*200 + n*16 + l15] = f2bf(p);
      }
      sum += __shfl_xor(sum,1); sum += __shfl_xor(sum,2);
      sum += __shfl_xor(sum,4); sum += __shfl_xor(sum,8);
      inv_[m][r] = 1.0f / sum;
    }
  }
  // zero P pad cols 176..191 for this wave's rows
  {
    s8v z8 = {0,0,0,0,0,0,0,0};
    for (int i = lane; i < nrf*16*2; i += 64){
      int rr = row0 + (i >> 1), cc = 176 + (i & 1)*8;
      *(s8v*)&Ps[rr*200 + cc] = z8;
    }
  }

  // O = P @ V — B-fragments straight from global V^T [d][ktok]
  f4v accO[3][8];
  #pragma unroll
  for (int m=0;m<3;m++)
    #pragma unroll
    for (int n=0;n<8;n++) accO[m][n] = zf;
  #pragma unroll
  for (int kf = 0; kf < 6; kf++){
    s8v ap[3];
    #pragma unroll
    for (int m=0;m<3;m++) if (m < nrf)
      ap[m] = *(const s8v*)&Ps[(row0 + m*16 + l15)*200 + kf*32 + lg*8];
    #pragma unroll
    for (int n=0;n<8;n++){
      s8v bv = *(const s8v*)(vtg + (size_t)(n*16 + l15)*168 + kf*32 + lg*8);
      #pragma unroll
      for (int m=0;m<3;m++) if (m < nrf)
        accO[m][n] = __builtin_amdgcn_mfma_f32_16x16x32_bf16(ap[m], bv, accO[m][n], 0,0,0);
    }
  }

  // write attn_out [b*168+q][hh*128+d] bf16 (normalize by 1/rowsum)
  #pragma unroll
  for (int m=0;m<3;m++){
    if (m >= nrf) continue;
    #pragma unroll
    for (int r=0;r<4;r++){
      int qtok = row0 + m*16 + lg*4 + r;
      if (qtok < 168){
        float iv = inv_[m][r];
        size_t base = ((size_t)b*168 + qtok)*512 + hh*128;
        #pragma unroll
        for (int n=0;n<8;n++)
          outp[base + n*16 + l15] = f2bf(accO[m][n][r] * iv);
      }
    }
  }
}

// ---------- launch ----------
extern "C" void kernel_launch(void* const* d_in, const int* in_sizes, int n_in,
                              void* d_out, int out_size, void* d_ws, size_t ws_size,
                              hipStream_t stream) {
  const float* x     = (const float*)d_in[0];
  const int*   valid = (const int*)  d_in[1];
  const float* wq    = (const float*)d_in[2];
  const float* bq    = (const float*)d_in[3];
  const float* wk    = (const float*)d_in[4];
  const float* bk    = (const float*)d_in[5];
  const float* wv    = (const float*)d_in[6];
  const float* bv    = (const float*)d_in[7];
  const float* fcw   = (const float*)d_in[8];
  const float* fcb   = (const float*)d_in[9];
  const float* ln1g  = (const float*)d_in[10];
  const float* ln1b  = (const float*)d_in[11];
  const float* ln2g  = (const float*)d_in[12];
  const float* ln2b  = (const float*)d_in[13];
  const float* fc1w  = (const float*)d_in[14];
  const float* fc1b  = (const float*)d_in[15];
  const float* fc2w  = (const float*)d_in[16];
  const float* fc2b  = (const float*)d_in[17];

  char* ws = (char*)d_ws;
  short* h       = (short*)(ws + 0LL);            // later: attn_out, then g2
  short* q_ws    = (short*)(ws + 176160768LL);    // later: y, then a1
  short* k_ws    = (short*)(ws + 352321536LL);    // later: x2 (fp32, spans k+vt)
  short* vt_ws   = (short*)(ws + 528482304LL);
  short* wb      = (short*)(ws + 704643072LL);    // bf16 weights [wq|wk|wv|fcw|fc1|fc2]
  short* attn_o  = h;
  short* y       = q_ws;
  float* x2      = (float*)(ws + 352321536LL);
  short* g2      = h;
  short* a1      = q_ws;
  float* outp    = (float*)d_out;

  convert_w<<<1536, 256, 0, stream>>>(wq, wk, wv, fcw, fc1w, fc2w, wb);
  ln1_kernel<<<MROWS/4, 256, 0, stream>>>(x, ln1g, ln1b, h);
  // QK projection (N=1024)
  gemm_bt<0><<<dim3(8, MROWS/128), 256, 0, stream>>>(h, wb, bq, bk, nullptr, q_ws, k_ws, nullptr);
  // V^T projection: wv @ h^T (M=512, N=172032)
  gemm_bt<1><<<dim3(4, MROWS/128), 256, 0, stream>>>(wb + 524288, h, bv, nullptr, nullptr, vt_ws, nullptr, nullptr);
  attn_kernel<<<BATCH*NHEAD, 256, 0, stream>>>(q_ws, k_ws, vt_ws, valid, attn_o);
  // output projection
  gemm_bt<2><<<dim3(4, MROWS/128), 256, 0, stream>>>(attn_o, wb + 786432, fcb, nullptr, nullptr, y, nullptr, nullptr);
  resid_ln<<<MROWS/4, 256, 0, stream>>>(x, y, ln2g, ln2b, x2, g2);
  // MLP
  gemm_bt<3><<<dim3(4, MROWS/128), 256, 0, stream>>>(g2, wb + 1048576, fc1b, nullptr, nullptr, a1, nullptr, nullptr);
  gemm_bt<4><<<dim3(4, MROWS/128), 256, 0, stream>>>(a1, wb + 1310720, fc2b, nullptr, x2, nullptr, nullptr, outp);
}

// Round 3
// 1791.430 us; speedup vs baseline: 1.0549x; 1.0349x over previous
//
#include <hip/hip_runtime.h>
#include <stdint.h>

// ---------- problem constants ----------
#define BATCH 1024
#define NVIEW 8
#define JN_   21
#define VTOK  168              // NVIEW*JN_
#define FDIM  512
#define NHEAD 4
#define DHEAD 128
#define MROWS (BATCH*VTOK)     // 172032
#define SCALE2 0.127517434f    // (1/sqrt(128)) * log2(e)

typedef __attribute__((ext_vector_type(8))) short s8v;
typedef __attribute__((ext_vector_type(4))) short s4v;
typedef __attribute__((ext_vector_type(4))) float f4v;

static __device__ __forceinline__ short f2bf(float f){
  unsigned u = __builtin_bit_cast(unsigned, f);
  unsigned r = (u + 0x7FFFu + ((u >> 16) & 1u)) >> 16;  // RNE
  return (short)(unsigned short)r;
}
static __device__ __forceinline__ float bf2f(short s){
  unsigned u = ((unsigned)(unsigned short)s) << 16;
  return __builtin_bit_cast(float, u);
}

#define GL16(gp, lp) __builtin_amdgcn_global_load_lds( \
    (__attribute__((address_space(1))) void*)(gp), \
    (__attribute__((address_space(3))) void*)(lp), 16, 0, 0)

// ---------- K0: fp32 -> bf16 weight conversion (wq|wk|wv|fcw|fc1|fc2) ----------
__global__ __launch_bounds__(256) void convert_w(
    const float* __restrict__ wq, const float* __restrict__ wk,
    const float* __restrict__ wv, const float* __restrict__ fcw,
    const float* __restrict__ fc1, const float* __restrict__ fc2,
    short* __restrict__ dst){
  int id = blockIdx.x * 256 + threadIdx.x;   // 393216 total
  int e = id * 4;
  int seg = e >> 18;            // 262144 elems per matrix
  int off = e & 262143;
  const float* s = seg==0?wq: seg==1?wk: seg==2?wv: seg==3?fcw: seg==4?fc1: fc2;
  float4 u = *(const float4*)(s + off);
  s4v o; o[0]=f2bf(u.x); o[1]=f2bf(u.y); o[2]=f2bf(u.z); o[3]=f2bf(u.w);
  *(s4v*)(dst + e) = o;
}

// ---------- K1: LN1 row kernel: h = LN(x) in bf16.  1 wave per row ----------
__global__ __launch_bounds__(256) void ln1_kernel(
    const float* __restrict__ x, const float* __restrict__ g,
    const float* __restrict__ bb, short* __restrict__ h){
  int row  = blockIdx.x * 4 + (threadIdx.x >> 6);
  int lane = threadIdx.x & 63;
  size_t base = (size_t)row * 512 + lane * 8;
  float4 u0 = *(const float4*)(x + base);
  float4 u1 = *(const float4*)(x + base + 4);
  float s = u0.x+u0.y+u0.z+u0.w + u1.x+u1.y+u1.z+u1.w;
  float q = u0.x*u0.x+u0.y*u0.y+u0.z*u0.z+u0.w*u0.w
          + u1.x*u1.x+u1.y*u1.y+u1.z*u1.z+u1.w*u1.w;
  #pragma unroll
  for (int o = 1; o < 64; o <<= 1){ s += __shfl_xor(s,o); q += __shfl_xor(q,o); }
  float mu = s * (1.f/512.f);
  float rstd = rsqrtf(q*(1.f/512.f) - mu*mu + 1e-6f);
  float4 g0 = *(const float4*)(g + lane*8),  g1 = *(const float4*)(g + lane*8 + 4);
  float4 b0 = *(const float4*)(bb + lane*8), b1 = *(const float4*)(bb + lane*8 + 4);
  s8v o_;
  o_[0]=f2bf((u0.x-mu)*rstd*g0.x+b0.x); o_[1]=f2bf((u0.y-mu)*rstd*g0.y+b0.y);
  o_[2]=f2bf((u0.z-mu)*rstd*g0.z+b0.z); o_[3]=f2bf((u0.w-mu)*rstd*g0.w+b0.w);
  o_[4]=f2bf((u1.x-mu)*rstd*g1.x+b1.x); o_[5]=f2bf((u1.y-mu)*rstd*g1.y+b1.y);
  o_[6]=f2bf((u1.z-mu)*rstd*g1.z+b1.z); o_[7]=f2bf((u1.w-mu)*rstd*g1.w+b1.w);
  *(s8v*)(h + base) = o_;
}

// ---------- K4b: g2 = LN2(x + y).  x2 not materialized (MODE4 re-reads x,y) ----------
__global__ __launch_bounds__(256) void resid_ln(
    const float* __restrict__ x, const short* __restrict__ y,
    const float* __restrict__ g, const float* __restrict__ bb,
    short* __restrict__ g2){
  int row  = blockIdx.x * 4 + (threadIdx.x >> 6);
  int lane = threadIdx.x & 63;
  size_t base = (size_t)row * 512 + lane * 8;
  float4 u0 = *(const float4*)(x + base);
  float4 u1 = *(const float4*)(x + base + 4);
  s8v yv = *(const s8v*)(y + base);
  float v[8];
  v[0]=u0.x+bf2f(yv[0]); v[1]=u0.y+bf2f(yv[1]); v[2]=u0.z+bf2f(yv[2]); v[3]=u0.w+bf2f(yv[3]);
  v[4]=u1.x+bf2f(yv[4]); v[5]=u1.y+bf2f(yv[5]); v[6]=u1.z+bf2f(yv[6]); v[7]=u1.w+bf2f(yv[7]);
  float s = 0.f, q = 0.f;
  #pragma unroll
  for (int i = 0; i < 8; i++){ s += v[i]; q += v[i]*v[i]; }
  #pragma unroll
  for (int o = 1; o < 64; o <<= 1){ s += __shfl_xor(s,o); q += __shfl_xor(q,o); }
  float mu = s * (1.f/512.f);
  float rstd = rsqrtf(q*(1.f/512.f) - mu*mu + 1e-6f);
  float4 g0 = *(const float4*)(g + lane*8),  g1 = *(const float4*)(g + lane*8 + 4);
  float4 b0 = *(const float4*)(bb + lane*8), b1 = *(const float4*)(bb + lane*8 + 4);
  s8v o_;
  o_[0]=f2bf((v[0]-mu)*rstd*g0.x+b0.x); o_[1]=f2bf((v[1]-mu)*rstd*g0.y+b0.y);
  o_[2]=f2bf((v[2]-mu)*rstd*g0.z+b0.z); o_[3]=f2bf((v[3]-mu)*rstd*g0.w+b0.w);
  o_[4]=f2bf((v[4]-mu)*rstd*g1.x+b1.x); o_[5]=f2bf((v[5]-mu)*rstd*g1.y+b1.y);
  o_[6]=f2bf((v[6]-mu)*rstd*g1.z+b1.z); o_[7]=f2bf((v[7]-mu)*rstd*g1.w+b1.w);
  *(s8v*)(g2 + base) = o_;
}

// ---------- GEMM v3: dbuf LDS + stage-before-compute + XOR bank swizzle ----------
// C[i][j] = sum_k A[i][k]*B[j][k], K=512, bf16 in, f32 acc.
// MODE 0: A=h, B=[wq|wk] -> q_ws/k_ws [B,NH,V,128] (+bq/bk)
// MODE 1: A=wv, B=h      -> vt_ws [B,NH,128,V]     (+bv)
// MODE 2: A=attn_out, B=fc_w -> y bf16 (+fc_b)
// MODE 3: A=g2, B=fc1_w  -> a1 = relu(.) bf16 (+fc1_b)
// MODE 4: A=a1, B=fc2_w  -> d_out f32 = . + fc2_b + x + y
template<int MODE>
__global__ __launch_bounds__(256) void gemm_bt(
    const short* __restrict__ A, const short* __restrict__ Bm,
    const float* __restrict__ bias0, const float* __restrict__ bias1,
    const float* __restrict__ aux, short* __restrict__ out0,
    short* __restrict__ out1, float* __restrict__ outf){
  __shared__ short As[2][8192];
  __shared__ short Bs[2][8192];
  int tid = threadIdx.x, lane = tid & 63;
  int wid = tid >> 6, wr = wid >> 1, wc = wid & 1;
  int lg = lane >> 4, l15 = lane & 15;
  // T1: XCD-aware bijective swizzle (nwg % 8 == 0 for all launches here)
  int nwg  = gridDim.x * gridDim.y;
  int flat = blockIdx.y * gridDim.x + blockIdx.x;
  int cpx  = nwg >> 3;
  int swz  = (flat & 7) * cpx + (flat >> 3);
  int bx = swz % gridDim.x, by = swz / gridDim.x;
  size_t mt, nt;
  if (MODE == 1){ mt = bx; nt = by; }
  else          { nt = bx; mt = by; }
  size_t m0 = mt * 128, n0 = nt * 128;
  const short* Ab = A + m0 * 512;
  const short* Bb = Bm + n0 * 512;
  f4v zf = {0.f,0.f,0.f,0.f};
  f4v acc[4][4];
  #pragma unroll
  for (int m=0;m<4;m++)
    #pragma unroll
    for (int n=0;n<4;n++) acc[m][n] = zf;

  // stage: thread covers 4 16B-chunks per matrix; LDS dest linear, global col
  // chunk XOR'd with row&7 (inverse swizzle) so swizzled ds_read sees logical data.
#define STAGE_G(bufi, kt) do {                                        \
    _Pragma("unroll")                                                 \
    for (int i_ = 0; i_ < 4; i_++){                                   \
      int c_ = tid + i_ * 256;                                        \
      int row_ = c_ >> 3;                                             \
      int chk_ = (c_ & 7) ^ (row_ & 7);                               \
      GL16(Ab + (size_t)row_*512 + (kt) + chk_*8, &As[bufi][c_*8]);   \
      GL16(Bb + (size_t)row_*512 + (kt) + chk_*8, &Bs[bufi][c_*8]);   \
    }                                                                 \
  } while(0)

#define COMPUTE_G(bufi) do {                                                     \
    _Pragma("unroll")                                                            \
    for (int kk8_ = 0; kk8_ < 8; kk8_ += 4){                                     \
      s8v af_[4], bf_[4];                                                        \
      int pc_ = ((kk8_ + lg) ^ (l15 & 7)) << 3;                                  \
      _Pragma("unroll")                                                          \
      for (int m_=0;m_<4;m_++) af_[m_] = *(const s8v*)&As[bufi][(wr*64+m_*16+l15)*64 + pc_]; \
      _Pragma("unroll")                                                          \
      for (int n_=0;n_<4;n_++) bf_[n_] = *(const s8v*)&Bs[bufi][(wc*64+n_*16+l15)*64 + pc_]; \
      _Pragma("unroll")                                                          \
      for (int m_=0;m_<4;m_++)                                                   \
        _Pragma("unroll")                                                        \
        for (int n_=0;n_<4;n_++)                                                 \
          acc[m_][n_] = __builtin_amdgcn_mfma_f32_16x16x32_bf16(af_[m_], bf_[n_], acc[m_][n_], 0,0,0); \
    }                                                                            \
  } while(0)

  STAGE_G(0, 0);
  __syncthreads();
  #pragma unroll
  for (int it = 0; it < 8; ++it){
    int cur = it & 1;
    if (it < 7) STAGE_G(cur ^ 1, (it + 1) * 64);
    COMPUTE_G(cur);
    if (it < 7) __syncthreads();
  }
#undef STAGE_G
#undef COMPUTE_G

  #pragma unroll
  for (int m=0;m<4;m++)
  #pragma unroll
  for (int n=0;n<4;n++)
  #pragma unroll
  for (int r=0;r<4;r++){
    int rowL = wr*64 + m*16 + lg*4 + r;
    int colL = wc*64 + n*16 + l15;
    size_t gm = m0 + rowL, gn = n0 + colL;
    float val = acc[m][n][r];
    if (MODE == 0){
      int nn = (int)gn;
      val += (nn < 512) ? bias0[nn] : bias1[nn - 512];
      int head = (nn >> 7) & 3, d = nn & 127;
      size_t b = gm / 168, tok = gm - b * 168;
      size_t idx = ((b*4 + head)*168 + tok)*128 + d;
      ((nn < 512) ? out0 : out1)[idx] = f2bf(val);
    } else if (MODE == 1){
      val += bias0[gm];
      int hh = ((int)gm >> 7) & 3, d = (int)gm & 127;
      size_t b = gn / 168, tok = gn - b * 168;
      out0[((b*4 + hh)*128 + d)*168 + tok] = f2bf(val);
    } else if (MODE == 2 || MODE == 3){
      val += bias0[gn];
      if (MODE == 3) val = fmaxf(val, 0.f);
      out0[gm*512 + gn] = f2bf(val);
    } else {
      val += bias0[gn] + aux[gm*512 + gn] + bf2f(out1[gm*512 + gn]);
      outf[gm*512 + gn] = val;
    }
  }
}

// ---------- K3 v3: attention; Q in regs, K/Vt reg-double-buffered, no barriers ----------
// One block per (b,head), 4 waves x 48 rows (uniform, rows >=168 discarded).
// LDS: P [192][200] bf16 = 76.8 KB -> 2 blocks/CU.
__global__ __launch_bounds__(256, 2) void attn_kernel(
    const short* __restrict__ qg_, const short* __restrict__ kg_,
    const short* __restrict__ vtg_, const int* __restrict__ valid,
    short* __restrict__ outp){
  __shared__ short Ps[192*200];

  int tid = threadIdx.x, lane = tid & 63, wid = tid >> 6;
  int lg = lane >> 4, l15 = lane & 15;
  int bh = blockIdx.x, b = bh >> 2, hh = bh & 3;
  const short* qg  = qg_  + (size_t)bh * (168*128);
  const short* kg  = kg_  + (size_t)bh * (168*128);
  const short* vtg = vtg_ + (size_t)bh * (128*168);

  // mask bits: bit v == 1 -> view v valid. All-invalid => constant shift => treat all valid.
  int bits = 0;
  #pragma unroll
  for (int v = 0; v < 8; v++) bits |= (valid[b*8 + v] != 0) << v;
  if (bits == 0) bits = 255;
  float wk2[11];
  #pragma unroll
  for (int n = 0; n < 11; n++){
    int kt = n*16 + l15;
    int view = (kt * 781) >> 14;            // kt/21, exact for kt<176
    wk2[n] = ((bits >> view) & 1) ? 0.0f : -1.0e9f;
  }

  int row0 = wid * 48;
  f4v zf = {0.f,0.f,0.f,0.f};

  // ---- preload Q fragments (rows >=168 read neighbor data; results discarded) ----
  s8v qf[3][4];
  #pragma unroll
  for (int m=0;m<3;m++)
    #pragma unroll
    for (int kf=0;kf<4;kf++)
      qf[m][kf] = *(const s8v*)(qg + (size_t)(row0 + m*16 + l15)*128 + kf*32 + lg*8);

  // ---- S = Q @ K^T with K register double-buffer ----
  f4v accS[3][11];
  #pragma unroll
  for (int m=0;m<3;m++)
    #pragma unroll
    for (int n=0;n<11;n++) accS[m][n] = zf;
  s8v kb[2][4];
  #pragma unroll
  for (int kf=0;kf<4;kf++)
    kb[0][kf] = *(const s8v*)(kg + (size_t)l15*128 + kf*32 + lg*8);
  #pragma unroll
  for (int n=0;n<11;n++){
    if (n < 10){
      #pragma unroll
      for (int kf=0;kf<4;kf++)
        kb[(n+1)&1][kf] = *(const s8v*)(kg + (size_t)((n+1)*16 + l15)*128 + kf*32 + lg*8);
    }
    __builtin_amdgcn_s_setprio(1);
    #pragma unroll
    for (int kf=0;kf<4;kf++)
      #pragma unroll
      for (int m=0;m<3;m++)
        accS[m][n] = __builtin_amdgcn_mfma_f32_16x16x32_bf16(qf[m][kf], kb[n&1][kf], accS[m][n], 0,0,0);
    __builtin_amdgcn_s_setprio(0);
  }

  // ---- softmax (shift-free: masked lanes get -1e9 in log2 domain) ----
  float inv_[3][4];
  #pragma unroll
  for (int m=0;m<3;m++){
    #pragma unroll
    for (int r=0;r<4;r++){
      int qtok = row0 + m*16 + lg*4 + r;
      float sum = 0.f;
      #pragma unroll
      for (int n=0;n<11;n++){
        float p = exp2f(fmaf(accS[m][n][r], SCALE2, wk2[n]));
        sum += p;
        Ps[qtok*200 + n*16 + l15] = f2bf(p);
      }
      sum += __shfl_xor(sum,1); sum += __shfl_xor(sum,2);
      sum += __shfl_xor(sum,4); sum += __shfl_xor(sum,8);
      inv_[m][r] = 1.0f / sum;
    }
  }
  // zero P pad cols 176..191 for this wave's 48 rows
  {
    s8v z8 = {0,0,0,0,0,0,0,0};
    for (int i = lane; i < 96; i += 64){
      int rr = row0 + (i >> 1);
      *(s8v*)&Ps[rr*200 + 176 + (i&1)*8] = z8;
    }
  }

  // ---- O = P @ V with Vt register double-buffer; P A-fragments hoisted ----
  s8v ap[3][6];
  #pragma unroll
  for (int m=0;m<3;m++)
    #pragma unroll
    for (int kf=0;kf<6;kf++)
      ap[m][kf] = *(const s8v*)&Ps[(row0 + m*16 + l15)*200 + kf*32 + lg*8];

  f4v accO[3][8];
  #pragma unroll
  for (int m=0;m<3;m++)
    #pragma unroll
    for (int n=0;n<8;n++) accO[m][n] = zf;
  s8v vb[2][6];
  #pragma unroll
  for (int kf=0;kf<6;kf++)
    vb[0][kf] = *(const s8v*)(vtg + (size_t)l15*168 + kf*32 + lg*8);
  #pragma unroll
  for (int n=0;n<8;n++){
    if (n < 7){
      #pragma unroll
      for (int kf=0;kf<6;kf++)
        vb[(n+1)&1][kf] = *(const s8v*)(vtg + (size_t)((n+1)*16 + l15)*168 + kf*32 + lg*8);
    }
    __builtin_amdgcn_s_setprio(1);
    #pragma unroll
    for (int kf=0;kf<6;kf++)
      #pragma unroll
      for (int m=0;m<3;m++)
        accO[m][n] = __builtin_amdgcn_mfma_f32_16x16x32_bf16(ap[m][kf], vb[n&1][kf], accO[m][n], 0,0,0);
    __builtin_amdgcn_s_setprio(0);
  }

  // ---- write attn_out [b*168+q][hh*128+d] bf16 (normalize) ----
  #pragma unroll
  for (int m=0;m<3;m++){
    #pragma unroll
    for (int r=0;r<4;r++){
      int qtok = row0 + m*16 + lg*4 + r;
      if (qtok < 168){
        float iv = inv_[m][r];
        size_t base = ((size_t)b*168 + qtok)*512 + hh*128;
        #pragma unroll
        for (int n=0;n<8;n++)
          outp[base + n*16 + l15] = f2bf(accO[m][n][r] * iv);
      }
    }
  }
}

// ---------- launch ----------
extern "C" void kernel_launch(void* const* d_in, const int* in_sizes, int n_in,
                              void* d_out, int out_size, void* d_ws, size_t ws_size,
                              hipStream_t stream) {
  const float* x     = (const float*)d_in[0];
  const int*   valid = (const int*)  d_in[1];
  const float* wq    = (const float*)d_in[2];
  const float* bq    = (const float*)d_in[3];
  const float* wk    = (const float*)d_in[4];
  const float* bk    = (const float*)d_in[5];
  const float* wv    = (const float*)d_in[6];
  const float* bv    = (const float*)d_in[7];
  const float* fcw   = (const float*)d_in[8];
  const float* fcb   = (const float*)d_in[9];
  const float* ln1g  = (const float*)d_in[10];
  const float* ln1b  = (const float*)d_in[11];
  const float* ln2g  = (const float*)d_in[12];
  const float* ln2b  = (const float*)d_in[13];
  const float* fc1w  = (const float*)d_in[14];
  const float* fc1b  = (const float*)d_in[15];
  const float* fc2w  = (const float*)d_in[16];
  const float* fc2b  = (const float*)d_in[17];

  char* ws = (char*)d_ws;
  short* h       = (short*)(ws + 0LL);            // later: attn_out, then g2
  short* q_ws    = (short*)(ws + 176160768LL);    // later: y
  short* k_ws    = (short*)(ws + 352321536LL);    // later: a1
  short* vt_ws   = (short*)(ws + 528482304LL);
  short* wb      = (short*)(ws + 704643072LL);    // bf16 weights [wq|wk|wv|fcw|fc1|fc2]
  short* attn_o  = h;
  short* y       = q_ws;
  short* g2      = h;
  short* a1      = k_ws;
  float* outp    = (float*)d_out;

  convert_w<<<1536, 256, 0, stream>>>(wq, wk, wv, fcw, fc1w, fc2w, wb);
  ln1_kernel<<<MROWS/4, 256, 0, stream>>>(x, ln1g, ln1b, h);
  // QK projection (N=1024)
  gemm_bt<0><<<dim3(8, MROWS/128), 256, 0, stream>>>(h, wb, bq, bk, nullptr, q_ws, k_ws, nullptr);
  // V^T projection: wv @ h^T (M=512, N=172032)
  gemm_bt<1><<<dim3(4, MROWS/128), 256, 0, stream>>>(wb + 524288, h, bv, nullptr, nullptr, vt_ws, nullptr, nullptr);
  attn_kernel<<<BATCH*NHEAD, 256, 0, stream>>>(q_ws, k_ws, vt_ws, valid, attn_o);
  // output projection
  gemm_bt<2><<<dim3(4, MROWS/128), 256, 0, stream>>>(attn_o, wb + 786432, fcb, nullptr, nullptr, y, nullptr, nullptr);
  resid_ln<<<MROWS/4, 256, 0, stream>>>(x, y, ln2g, ln2b, g2);
  // MLP
  gemm_bt<3><<<dim3(4, MROWS/128), 256, 0, stream>>>(g2, wb + 1048576, fc1b, nullptr, nullptr, a1, nullptr, nullptr);
  gemm_bt<4><<<dim3(4, MROWS/128), 256, 0, stream>>>(a1, wb + 1310720, fc2b, nullptr, (float*)x, nullptr, y, outp);
}

// Round 4
// 1526.841 us; speedup vs baseline: 1.2377x; 1.1733x over previous
//
#include <hip/hip_runtime.h>
#include <stdint.h>

// ---------- problem constants ----------
#define BATCH 1024
#define NVIEW 8
#define JN_   21
#define VTOK  168              // NVIEW*JN_
#define FDIM  512
#define NHEAD 4
#define DHEAD 128
#define MROWS (BATCH*VTOK)     // 172032
#define SCALE2 0.127517434f    // (1/sqrt(128)) * log2(e)

typedef __attribute__((ext_vector_type(8))) short s8v;
typedef __attribute__((ext_vector_type(4))) short s4v;
typedef __attribute__((ext_vector_type(4))) float f4v;

static __device__ __forceinline__ short f2bf(float f){
  unsigned u = __builtin_bit_cast(unsigned, f);
  unsigned r = (u + 0x7FFFu + ((u >> 16) & 1u)) >> 16;  // RNE
  return (short)(unsigned short)r;
}
static __device__ __forceinline__ float bf2f(short s){
  unsigned u = ((unsigned)(unsigned short)s) << 16;
  return __builtin_bit_cast(float, u);
}

#define GL16(gp, lp) __builtin_amdgcn_global_load_lds( \
    (__attribute__((address_space(1))) void*)(gp), \
    (__attribute__((address_space(3))) void*)(lp), 16, 0, 0)

// ---------- K0: fp32 -> bf16 weight conversion (wq|wk|wv|fcw|fc1|fc2) ----------
__global__ __launch_bounds__(256) void convert_w(
    const float* __restrict__ wq, const float* __restrict__ wk,
    const float* __restrict__ wv, const float* __restrict__ fcw,
    const float* __restrict__ fc1, const float* __restrict__ fc2,
    short* __restrict__ dst){
  int id = blockIdx.x * 256 + threadIdx.x;   // 393216 total
  int e = id * 4;
  int seg = e >> 18;            // 262144 elems per matrix
  int off = e & 262143;
  const float* s = seg==0?wq: seg==1?wk: seg==2?wv: seg==3?fcw: seg==4?fc1: fc2;
  float4 u = *(const float4*)(s + off);
  s4v o; o[0]=f2bf(u.x); o[1]=f2bf(u.y); o[2]=f2bf(u.z); o[3]=f2bf(u.w);
  *(s4v*)(dst + e) = o;
}

// ---------- K1: LN1 row kernel: h = LN(x) in bf16.  1 wave per row ----------
__global__ __launch_bounds__(256) void ln1_kernel(
    const float* __restrict__ x, const float* __restrict__ g,
    const float* __restrict__ bb, short* __restrict__ h){
  int row  = blockIdx.x * 4 + (threadIdx.x >> 6);
  int lane = threadIdx.x & 63;
  size_t base = (size_t)row * 512 + lane * 8;
  float4 u0 = *(const float4*)(x + base);
  float4 u1 = *(const float4*)(x + base + 4);
  float s = u0.x+u0.y+u0.z+u0.w + u1.x+u1.y+u1.z+u1.w;
  float q = u0.x*u0.x+u0.y*u0.y+u0.z*u0.z+u0.w*u0.w
          + u1.x*u1.x+u1.y*u1.y+u1.z*u1.z+u1.w*u1.w;
  #pragma unroll
  for (int o = 1; o < 64; o <<= 1){ s += __shfl_xor(s,o); q += __shfl_xor(q,o); }
  float mu = s * (1.f/512.f);
  float rstd = rsqrtf(q*(1.f/512.f) - mu*mu + 1e-6f);
  float4 g0 = *(const float4*)(g + lane*8),  g1 = *(const float4*)(g + lane*8 + 4);
  float4 b0 = *(const float4*)(bb + lane*8), b1 = *(const float4*)(bb + lane*8 + 4);
  s8v o_;
  o_[0]=f2bf((u0.x-mu)*rstd*g0.x+b0.x); o_[1]=f2bf((u0.y-mu)*rstd*g0.y+b0.y);
  o_[2]=f2bf((u0.z-mu)*rstd*g0.z+b0.z); o_[3]=f2bf((u0.w-mu)*rstd*g0.w+b0.w);
  o_[4]=f2bf((u1.x-mu)*rstd*g1.x+b1.x); o_[5]=f2bf((u1.y-mu)*rstd*g1.y+b1.y);
  o_[6]=f2bf((u1.z-mu)*rstd*g1.z+b1.z); o_[7]=f2bf((u1.w-mu)*rstd*g1.w+b1.w);
  *(s8v*)(h + base) = o_;
}

// ---------- K4b: g2 = LN2(x + y).  x2 not materialized (MODE4 re-reads x,y) ----------
__global__ __launch_bounds__(256) void resid_ln(
    const float* __restrict__ x, const short* __restrict__ y,
    const float* __restrict__ g, const float* __restrict__ bb,
    short* __restrict__ g2){
  int row  = blockIdx.x * 4 + (threadIdx.x >> 6);
  int lane = threadIdx.x & 63;
  size_t base = (size_t)row * 512 + lane * 8;
  float4 u0 = *(const float4*)(x + base);
  float4 u1 = *(const float4*)(x + base + 4);
  s8v yv = *(const s8v*)(y + base);
  float v[8];
  v[0]=u0.x+bf2f(yv[0]); v[1]=u0.y+bf2f(yv[1]); v[2]=u0.z+bf2f(yv[2]); v[3]=u0.w+bf2f(yv[3]);
  v[4]=u1.x+bf2f(yv[4]); v[5]=u1.y+bf2f(yv[5]); v[6]=u1.z+bf2f(yv[6]); v[7]=u1.w+bf2f(yv[7]);
  float s = 0.f, q = 0.f;
  #pragma unroll
  for (int i = 0; i < 8; i++){ s += v[i]; q += v[i]*v[i]; }
  #pragma unroll
  for (int o = 1; o < 64; o <<= 1){ s += __shfl_xor(s,o); q += __shfl_xor(q,o); }
  float mu = s * (1.f/512.f);
  float rstd = rsqrtf(q*(1.f/512.f) - mu*mu + 1e-6f);
  float4 g0 = *(const float4*)(g + lane*8),  g1 = *(const float4*)(g + lane*8 + 4);
  float4 b0 = *(const float4*)(bb + lane*8), b1 = *(const float4*)(bb + lane*8 + 4);
  s8v o_;
  o_[0]=f2bf((v[0]-mu)*rstd*g0.x+b0.x); o_[1]=f2bf((v[1]-mu)*rstd*g0.y+b0.y);
  o_[2]=f2bf((v[2]-mu)*rstd*g0.z+b0.z); o_[3]=f2bf((v[3]-mu)*rstd*g0.w+b0.w);
  o_[4]=f2bf((v[4]-mu)*rstd*g1.x+b1.x); o_[5]=f2bf((v[5]-mu)*rstd*g1.y+b1.y);
  o_[6]=f2bf((v[6]-mu)*rstd*g1.z+b1.z); o_[7]=f2bf((v[7]-mu)*rstd*g1.w+b1.w);
  *(s8v*)(g2 + base) = o_;
}

// ---------- GEMM v4: 3-deep K-tile pipeline, counted vmcnt, never drain ----------
// BM=256, BN=128, BK=64; 512 threads = 8 waves (4M x 2N), 64x64 per wave.
// C[i][j] = sum_k A[i][k]*B[j][k], K=512 (8 K-tiles), bf16 in, f32 acc.
// Pipeline: 3 LDS buffers; iter t: vmcnt(12) [tile t landed; t+1,t+2 in flight]
// -> s_barrier -> compute tile t -> s_barrier -> issue tile t+3 into buf[t%3].
template<int MODE>
__global__ __launch_bounds__(512) void gemm_bt(
    const short* __restrict__ A, const short* __restrict__ Bm,
    const float* __restrict__ bias0, const float* __restrict__ bias1,
    const float* __restrict__ aux, short* __restrict__ out0,
    short* __restrict__ out1, float* __restrict__ outf){
  __shared__ short As[3][16384];   // [buf][256 rows * 64 cols]
  __shared__ short Bs[3][8192];    // [buf][128 rows * 64 cols]
  int tid = threadIdx.x, lane = tid & 63;
  int wid = tid >> 6, wr = wid >> 1, wc = wid & 1;   // 4M x 2N waves
  int lg = lane >> 4, l15 = lane & 15;
  // T1: XCD-aware bijective swizzle (nwg % 8 == 0 for all launches here)
  int nwg  = gridDim.x * gridDim.y;
  int flat = blockIdx.y * gridDim.x + blockIdx.x;
  int cpx  = nwg >> 3;
  int swz  = (flat & 7) * cpx + (flat >> 3);
  int bx = swz % gridDim.x, by = swz / gridDim.x;
  size_t mt, nt;
  if (MODE == 1){ mt = bx; nt = by; }
  else          { nt = bx; mt = by; }
  size_t m0 = mt * 256, n0 = nt * 128;
  const short* Ab = A + m0 * 512;
  const short* Bb = Bm + n0 * 512;
  f4v zf = {0.f,0.f,0.f,0.f};
  f4v acc[4][4];
  #pragma unroll
  for (int m=0;m<4;m++)
    #pragma unroll
    for (int n=0;n<4;n++) acc[m][n] = zf;

  // stage one K-tile (A: 4 rounds, B: 2 rounds; 6 loads/thread). LDS dest is
  // linear; global column-chunk XOR'd with row&7 (inverse of read swizzle).
#define STAGE_T(bufi, kt) do {                                        \
    _Pragma("unroll")                                                 \
    for (int r_ = 0; r_ < 4; r_++){                                   \
      int c_ = r_*512 + tid;                                          \
      int row_ = c_ >> 3;                                             \
      int chk_ = (c_ & 7) ^ (row_ & 7);                               \
      GL16(Ab + (size_t)row_*512 + (kt) + chk_*8, &As[bufi][c_*8]);   \
    }                                                                 \
    _Pragma("unroll")                                                 \
    for (int r_ = 0; r_ < 2; r_++){                                   \
      int c_ = r_*512 + tid;                                          \
      int row_ = c_ >> 3;                                             \
      int chk_ = (c_ & 7) ^ (row_ & 7);                               \
      GL16(Bb + (size_t)row_*512 + (kt) + chk_*8, &Bs[bufi][c_*8]);   \
    }                                                                 \
  } while(0)

  STAGE_T(0, 0); STAGE_T(1, 64); STAGE_T(2, 128);

  #pragma unroll
  for (int t = 0; t < 8; ++t){
    if (t < 6)       asm volatile("s_waitcnt vmcnt(12)" ::: "memory");
    else if (t == 6) asm volatile("s_waitcnt vmcnt(6)"  ::: "memory");
    else             asm volatile("s_waitcnt vmcnt(0)"  ::: "memory");
    __builtin_amdgcn_s_barrier();
    __builtin_amdgcn_sched_barrier(0);
    {
      const short* Ap = As[t % 3];
      const short* Bp = Bs[t % 3];
      #pragma unroll
      for (int kk8 = 0; kk8 < 8; kk8 += 4){
        s8v af_[4], bf_[4];
        int pc_ = ((kk8 + lg) ^ (l15 & 7)) << 3;
        #pragma unroll
        for (int m_=0;m_<4;m_++) af_[m_] = *(const s8v*)&Ap[(wr*64+m_*16+l15)*64 + pc_];
        #pragma unroll
        for (int n_=0;n_<4;n_++) bf_[n_] = *(const s8v*)&Bp[(wc*64+n_*16+l15)*64 + pc_];
        __builtin_amdgcn_s_setprio(1);
        #pragma unroll
        for (int m_=0;m_<4;m_++)
          #pragma unroll
          for (int n_=0;n_<4;n_++)
            acc[m_][n_] = __builtin_amdgcn_mfma_f32_16x16x32_bf16(af_[m_], bf_[n_], acc[m_][n_], 0,0,0);
        __builtin_amdgcn_s_setprio(0);
      }
    }
    if (t < 5){
      __builtin_amdgcn_s_barrier();        // all waves done reading buf[t%3]
      __builtin_amdgcn_sched_barrier(0);
      STAGE_T((t + 3) % 3, (t + 3) * 64);  // refill freed buffer
    }
  }
#undef STAGE_T

  #pragma unroll
  for (int m=0;m<4;m++)
  #pragma unroll
  for (int n=0;n<4;n++)
  #pragma unroll
  for (int r=0;r<4;r++){
    int rowL = wr*64 + m*16 + lg*4 + r;
    int colL = wc*64 + n*16 + l15;
    size_t gm = m0 + rowL, gn = n0 + colL;
    float val = acc[m][n][r];
    if (MODE == 0){
      int nn = (int)gn;
      val += (nn < 512) ? bias0[nn] : bias1[nn - 512];
      int head = (nn >> 7) & 3, d = nn & 127;
      size_t b = gm / 168, tok = gm - b * 168;
      size_t idx = ((b*4 + head)*168 + tok)*128 + d;
      ((nn < 512) ? out0 : out1)[idx] = f2bf(val);
    } else if (MODE == 1){
      val += bias0[gm];
      int hh = ((int)gm >> 7) & 3, d = (int)gm & 127;
      size_t b = gn / 168, tok = gn - b * 168;
      out0[((b*4 + hh)*128 + d)*168 + tok] = f2bf(val);
    } else if (MODE == 2 || MODE == 3){
      val += bias0[gn];
      if (MODE == 3) val = fmaxf(val, 0.f);
      out0[gm*512 + gn] = f2bf(val);
    } else {
      val += bias0[gn] + aux[gm*512 + gn] + bf2f(out1[gm*512 + gn]);
      outf[gm*512 + gn] = val;
    }
  }
}

// ---------- K3 v3: attention; Q in regs, K/Vt reg-double-buffered, no barriers ----------
// One block per (b,head), 4 waves x 48 rows (uniform, rows >=168 discarded).
// LDS: P [192][200] bf16 = 76.8 KB -> 2 blocks/CU.
__global__ __launch_bounds__(256, 2) void attn_kernel(
    const short* __restrict__ qg_, const short* __restrict__ kg_,
    const short* __restrict__ vtg_, const int* __restrict__ valid,
    short* __restrict__ outp){
  __shared__ short Ps[192*200];

  int tid = threadIdx.x, lane = tid & 63, wid = tid >> 6;
  int lg = lane >> 4, l15 = lane & 15;
  int bh = blockIdx.x, b = bh >> 2, hh = bh & 3;
  const short* qg  = qg_  + (size_t)bh * (168*128);
  const short* kg  = kg_  + (size_t)bh * (168*128);
  const short* vtg = vtg_ + (size_t)bh * (128*168);

  // mask bits: bit v == 1 -> view v valid. All-invalid => constant shift => treat all valid.
  int bits = 0;
  #pragma unroll
  for (int v = 0; v < 8; v++) bits |= (valid[b*8 + v] != 0) << v;
  if (bits == 0) bits = 255;
  float wk2[11];
  #pragma unroll
  for (int n = 0; n < 11; n++){
    int kt = n*16 + l15;
    int view = (kt * 781) >> 14;            // kt/21, exact for kt<176
    wk2[n] = ((bits >> view) & 1) ? 0.0f : -1.0e9f;
  }

  int row0 = wid * 48;
  f4v zf = {0.f,0.f,0.f,0.f};

  // ---- preload Q fragments (rows >=168 read neighbor data; results discarded) ----
  s8v qf[3][4];
  #pragma unroll
  for (int m=0;m<3;m++)
    #pragma unroll
    for (int kf=0;kf<4;kf++)
      qf[m][kf] = *(const s8v*)(qg + (size_t)(row0 + m*16 + l15)*128 + kf*32 + lg*8);

  // ---- S = Q @ K^T with K register double-buffer ----
  f4v accS[3][11];
  #pragma unroll
  for (int m=0;m<3;m++)
    #pragma unroll
    for (int n=0;n<11;n++) accS[m][n] = zf;
  s8v kb[2][4];
  #pragma unroll
  for (int kf=0;kf<4;kf++)
    kb[0][kf] = *(const s8v*)(kg + (size_t)l15*128 + kf*32 + lg*8);
  #pragma unroll
  for (int n=0;n<11;n++){
    if (n < 10){
      #pragma unroll
      for (int kf=0;kf<4;kf++)
        kb[(n+1)&1][kf] = *(const s8v*)(kg + (size_t)((n+1)*16 + l15)*128 + kf*32 + lg*8);
    }
    __builtin_amdgcn_s_setprio(1);
    #pragma unroll
    for (int kf=0;kf<4;kf++)
      #pragma unroll
      for (int m=0;m<3;m++)
        accS[m][n] = __builtin_amdgcn_mfma_f32_16x16x32_bf16(qf[m][kf], kb[n&1][kf], accS[m][n], 0,0,0);
    __builtin_amdgcn_s_setprio(0);
  }

  // ---- softmax (shift-free: masked lanes get -1e9 in log2 domain) ----
  float inv_[3][4];
  #pragma unroll
  for (int m=0;m<3;m++){
    #pragma unroll
    for (int r=0;r<4;r++){
      int qtok = row0 + m*16 + lg*4 + r;
      float sum = 0.f;
      #pragma unroll
      for (int n=0;n<11;n++){
        float p = exp2f(fmaf(accS[m][n][r], SCALE2, wk2[n]));
        sum += p;
        Ps[qtok*200 + n*16 + l15] = f2bf(p);
      }
      sum += __shfl_xor(sum,1); sum += __shfl_xor(sum,2);
      sum += __shfl_xor(sum,4); sum += __shfl_xor(sum,8);
      inv_[m][r] = 1.0f / sum;
    }
  }
  // zero P pad cols 176..191 for this wave's 48 rows
  {
    s8v z8 = {0,0,0,0,0,0,0,0};
    for (int i = lane; i < 96; i += 64){
      int rr = row0 + (i >> 1);
      *(s8v*)&Ps[rr*200 + 176 + (i&1)*8] = z8;
    }
  }

  // ---- O = P @ V with Vt register double-buffer; P A-fragments hoisted ----
  s8v ap[3][6];
  #pragma unroll
  for (int m=0;m<3;m++)
    #pragma unroll
    for (int kf=0;kf<6;kf++)
      ap[m][kf] = *(const s8v*)&Ps[(row0 + m*16 + l15)*200 + kf*32 + lg*8];

  f4v accO[3][8];
  #pragma unroll
  for (int m=0;m<3;m++)
    #pragma unroll
    for (int n=0;n<8;n++) accO[m][n] = zf;
  s8v vb[2][6];
  #pragma unroll
  for (int kf=0;kf<6;kf++)
    vb[0][kf] = *(const s8v*)(vtg + (size_t)l15*168 + kf*32 + lg*8);
  #pragma unroll
  for (int n=0;n<8;n++){
    if (n < 7){
      #pragma unroll
      for (int kf=0;kf<6;kf++)
        vb[(n+1)&1][kf] = *(const s8v*)(vtg + (size_t)((n+1)*16 + l15)*168 + kf*32 + lg*8);
    }
    __builtin_amdgcn_s_setprio(1);
    #pragma unroll
    for (int kf=0;kf<6;kf++)
      #pragma unroll
      for (int m=0;m<3;m++)
        accO[m][n] = __builtin_amdgcn_mfma_f32_16x16x32_bf16(ap[m][kf], vb[n&1][kf], accO[m][n], 0,0,0);
    __builtin_amdgcn_s_setprio(0);
  }

  // ---- write attn_out [b*168+q][hh*128+d] bf16 (normalize) ----
  #pragma unroll
  for (int m=0;m<3;m++){
    #pragma unroll
    for (int r=0;r<4;r++){
      int qtok = row0 + m*16 + lg*4 + r;
      if (qtok < 168){
        float iv = inv_[m][r];
        size_t base = ((size_t)b*168 + qtok)*512 + hh*128;
        #pragma unroll
        for (int n=0;n<8;n++)
          outp[base + n*16 + l15] = f2bf(accO[m][n][r] * iv);
      }
    }
  }
}

// ---------- launch ----------
extern "C" void kernel_launch(void* const* d_in, const int* in_sizes, int n_in,
                              void* d_out, int out_size, void* d_ws, size_t ws_size,
                              hipStream_t stream) {
  const float* x     = (const float*)d_in[0];
  const int*   valid = (const int*)  d_in[1];
  const float* wq    = (const float*)d_in[2];
  const float* bq    = (const float*)d_in[3];
  const float* wk    = (const float*)d_in[4];
  const float* bk    = (const float*)d_in[5];
  const float* wv    = (const float*)d_in[6];
  const float* bv    = (const float*)d_in[7];
  const float* fcw   = (const float*)d_in[8];
  const float* fcb   = (const float*)d_in[9];
  const float* ln1g  = (const float*)d_in[10];
  const float* ln1b  = (const float*)d_in[11];
  const float* ln2g  = (const float*)d_in[12];
  const float* ln2b  = (const float*)d_in[13];
  const float* fc1w  = (const float*)d_in[14];
  const float* fc1b  = (const float*)d_in[15];
  const float* fc2w  = (const float*)d_in[16];
  const float* fc2b  = (const float*)d_in[17];

  char* ws = (char*)d_ws;
  short* h       = (short*)(ws + 0LL);            // later: attn_out, then g2
  short* q_ws    = (short*)(ws + 176160768LL);    // later: y
  short* k_ws    = (short*)(ws + 352321536LL);    // later: a1
  short* vt_ws   = (short*)(ws + 528482304LL);
  short* wb      = (short*)(ws + 704643072LL);    // bf16 weights [wq|wk|wv|fcw|fc1|fc2]
  short* attn_o  = h;
  short* y       = q_ws;
  short* g2      = h;
  short* a1      = k_ws;
  float* outp    = (float*)d_out;

  convert_w<<<1536, 256, 0, stream>>>(wq, wk, wv, fcw, fc1w, fc2w, wb);
  ln1_kernel<<<MROWS/4, 256, 0, stream>>>(x, ln1g, ln1b, h);
  // QK projection (N=1024): M-tiles 672, N-tiles 8
  gemm_bt<0><<<dim3(8, MROWS/256), 512, 0, stream>>>(h, wb, bq, bk, nullptr, q_ws, k_ws, nullptr);
  // V^T projection: wv @ h^T (M=512 -> 2 M-tiles, N=172032 -> 1344 N-tiles)
  gemm_bt<1><<<dim3(2, MROWS/128), 512, 0, stream>>>(wb + 524288, h, bv, nullptr, nullptr, vt_ws, nullptr, nullptr);
  attn_kernel<<<BATCH*NHEAD, 256, 0, stream>>>(q_ws, k_ws, vt_ws, valid, attn_o);
  // output projection
  gemm_bt<2><<<dim3(4, MROWS/256), 512, 0, stream>>>(attn_o, wb + 786432, fcb, nullptr, nullptr, y, nullptr, nullptr);
  resid_ln<<<MROWS/4, 256, 0, stream>>>(x, y, ln2g, ln2b, g2);
  // MLP
  gemm_bt<3><<<dim3(4, MROWS/256), 512, 0, stream>>>(g2, wb + 1048576, fc1b, nullptr, nullptr, a1, nullptr, nullptr);
  gemm_bt<4><<<dim3(4, MROWS/256), 512, 0, stream>>>(a1, wb + 1310720, fc2b, nullptr, (float*)x, nullptr, y, outp);
}